// Round 1
// baseline (584.895 us; speedup 1.0000x reference)
//
#include <hip/hip_runtime.h>
#include <hip/hip_bf16.h>
#include <cstddef>

#define B_   8
#define CIN  96
#define H_   256
#define W_   256
#define CO1  48          // conv1 output channels
#define NCH  192         // final output channels (CO1*4)
#define HO   128
#define WO   128
#define HP   258         // padded NHWC height/width (1-px zero halo)

typedef short  v8s __attribute__((ext_vector_type(8)));   // 8 x bf16 (4 VGPRs)
typedef float  v4f __attribute__((ext_vector_type(4)));   // MFMA acc frag

static __device__ __forceinline__ unsigned short f2bf(float f) {
    __hip_bfloat16 h = __float2bfloat16(f);   // RNE
    return *(unsigned short*)&h;
}
static __device__ __forceinline__ float bf2f(unsigned short u) {
    return __uint_as_float(((unsigned int)u) << 16);
}

// ---------------------------------------------------------------------------
// Merged prep: weights repack + mask pixel-unshuffle + xt halo zero.
// One launch instead of three (launch overhead x3 -> x1).
//   range [0, N1):        w_body[co][ci][kh][kw] fp32 -> wbf[tap][co][ci] bf16
//   range [N1, N1+N2):    mask (8,1,256,256) -> m_us (8,4,128,128) fp32
//   range [N1+N2, ..+N3): zero 1-px halo border of xt (ws poisoned each launch)
// ---------------------------------------------------------------------------
#define N1 (9 * CO1 * CIN)                 // 41472
#define N2 (B_ * 4 * HO * WO)              // 524288
#define NPIX (2 * HP + 2 * (HP - 2))       // 1028 border pixels
#define N3 (B_ * NPIX * CIN)               // 789504

__global__ void prep_all(const float* __restrict__ wb, unsigned short* __restrict__ wbf,
                         const float* __restrict__ mask, float* __restrict__ m_us,
                         unsigned short* __restrict__ xt) {
    int o = blockIdx.x * blockDim.x + threadIdx.x;
    if (o < N1) {
        int ci  = o % CIN;
        int co  = (o / CIN) % CO1;
        int tap = o / (CIN * CO1);
        wbf[o] = f2bf(wb[(co * CIN + ci) * 9 + tap]);
    } else if (o < N1 + N2) {
        int m = o - N1;
        int w1 = m & (WO - 1);
        int h1 = (m >> 7) & (HO - 1);
        int q  = (m >> 14) & 3;                         // 2*dy + dx
        int b  = m >> 16;
        int dy = q >> 1, dx = q & 1;
        m_us[m] = mask[((size_t)b * H_ + (2 * h1 + dy)) * W_ + (2 * w1 + dx)];
    } else if (o < N1 + N2 + N3) {
        int z = o - N1 - N2;
        int ci = z % CIN;
        int p  = (z / CIN) % NPIX;
        int b  = z / (CIN * NPIX);
        int r, c;
        if      (p < HP)          { r = 0;            c = p; }
        else if (p < 2 * HP)      { r = HP - 1;       c = p - HP; }
        else if (p < 2 * HP + 256){ r = p - 2*HP + 1; c = 0; }
        else                      { r = p - (2*HP + 256) + 1; c = HP - 1; }
        xt[(((size_t)b * HP + r) * HP + c) * CIN + ci] = 0;
    }
}

// ---------------------------------------------------------------------------
// x (8,96,256,256) fp32 NCHW -> xt bf16 NHWC (8,258,258,96), interior.
// One thread per pixel: 96 coalesced dword loads, 12 dwordx4 stores.
// ---------------------------------------------------------------------------
__global__ __launch_bounds__(256) void transpose_x(const float* __restrict__ x,
                                                   unsigned short* __restrict__ xt) {
    int t = blockIdx.x * blockDim.x + threadIdx.x;      // flat over 8*65536
    int pix = t & (H_ * W_ - 1);
    int b   = t >> 16;
    int h   = pix >> 8, w = pix & 255;

    unsigned int vals[CIN / 2];
#pragma unroll
    for (int ci = 0; ci < CIN; ci += 2) {
        float f0 = x[(((size_t)b * CIN + ci)     << 16) + pix];
        float f1 = x[(((size_t)b * CIN + ci + 1) << 16) + pix];
        vals[ci >> 1] = (unsigned int)f2bf(f0) | ((unsigned int)f2bf(f1) << 16);
    }
    unsigned short* dst = xt + (((size_t)b * HP + (h + 1)) * HP + (w + 1)) * CIN;
#pragma unroll
    for (int j = 0; j < 12; ++j)
        ((int4*)dst)[j] = ((const int4*)vals)[j];
}

// ---------------------------------------------------------------------------
// conv1: implicit GEMM via MFMA. A = weights (M=48 co), B = pixels (N),
// K = 9 taps x 96 ci. Block = 4 waves, each wave = 64 consecutive W pixels
// of one row. No LDS, no barriers.
// XCD swizzle: flat block id round-robins XCDs (%8); remap so XCD k streams
// batch k's rows 0..255 in order -> rows h-1..h+1 re-reads hit that XCD's L2
// (fetch 3.7x -> ~1.1x, HBM ~900cy misses -> L2 ~200cy hits).
// Output y_us now bf16 (error ~7e-5 after conv2's 0.02-scale weights).
// ---------------------------------------------------------------------------
__global__ __launch_bounds__(256) void conv1_mfma(const unsigned short* __restrict__ xt,
                                                  const unsigned short* __restrict__ wbf,
                                                  unsigned short* __restrict__ y_us) {
    const int flat = blockIdx.x;                    // 0..2047
    const int j    = (flat & 7) * 256 + (flat >> 3);
    const int b    = j >> 8;                        // == flat & 7 (one batch per XCD)
    const int h    = j & 255;                       // output row, sequential per XCD

    const int tid  = threadIdx.x;
    const int lane = tid & 63;
    const int wv   = tid >> 6;
    const int w0   = wv * 64;
    const int l15  = lane & 15;
    const int l4   = lane >> 4;

    // per-lane base addresses (element units)
    const unsigned short* aln = wbf + (l15 * CIN + l4 * 8);
    const unsigned short* bln = xt + (((size_t)b * HP + h) * HP + w0) * CIN
                                   + ((size_t)l15 * CIN + l4 * 8);

    v4f acc[12];
#pragma unroll
    for (int i = 0; i < 12; ++i) acc[i] = (v4f){0.f, 0.f, 0.f, 0.f};

    for (int tap = 0; tap < 9; ++tap) {
        const int kh = tap / 3, kw = tap % 3;
        const unsigned short* bt = bln + ((size_t)kh * HP + kw) * CIN;
        const unsigned short* at = aln + (size_t)tap * CO1 * CIN;
#pragma unroll
        for (int ks = 0; ks < 3; ++ks) {
            v8s a0 = *(const v8s*)(at +  0 * CIN + ks * 32);
            v8s a1 = *(const v8s*)(at + 16 * CIN + ks * 32);
            v8s a2 = *(const v8s*)(at + 32 * CIN + ks * 32);
            v8s b0 = *(const v8s*)(bt +  0 * CIN + ks * 32);
            v8s b1 = *(const v8s*)(bt + 16 * CIN + ks * 32);
            v8s b2 = *(const v8s*)(bt + 32 * CIN + ks * 32);
            v8s b3 = *(const v8s*)(bt + 48 * CIN + ks * 32);
            acc[0]  = __builtin_amdgcn_mfma_f32_16x16x32_bf16(a0, b0, acc[0],  0, 0, 0);
            acc[1]  = __builtin_amdgcn_mfma_f32_16x16x32_bf16(a0, b1, acc[1],  0, 0, 0);
            acc[2]  = __builtin_amdgcn_mfma_f32_16x16x32_bf16(a0, b2, acc[2],  0, 0, 0);
            acc[3]  = __builtin_amdgcn_mfma_f32_16x16x32_bf16(a0, b3, acc[3],  0, 0, 0);
            acc[4]  = __builtin_amdgcn_mfma_f32_16x16x32_bf16(a1, b0, acc[4],  0, 0, 0);
            acc[5]  = __builtin_amdgcn_mfma_f32_16x16x32_bf16(a1, b1, acc[5],  0, 0, 0);
            acc[6]  = __builtin_amdgcn_mfma_f32_16x16x32_bf16(a1, b2, acc[6],  0, 0, 0);
            acc[7]  = __builtin_amdgcn_mfma_f32_16x16x32_bf16(a1, b3, acc[7],  0, 0, 0);
            acc[8]  = __builtin_amdgcn_mfma_f32_16x16x32_bf16(a2, b0, acc[8],  0, 0, 0);
            acc[9]  = __builtin_amdgcn_mfma_f32_16x16x32_bf16(a2, b1, acc[9],  0, 0, 0);
            acc[10] = __builtin_amdgcn_mfma_f32_16x16x32_bf16(a2, b2, acc[10], 0, 0, 0);
            acc[11] = __builtin_amdgcn_mfma_f32_16x16x32_bf16(a2, b3, acc[11], 0, 0, 0);
        }
    }

    // Epilogue: D row = co = mf*16 + l4*4 + r ; D col = pixel = w0 + nf*16 + l15
    const int dy = h & 1, hp1 = h >> 1;
#pragma unroll
    for (int mf = 0; mf < 3; ++mf) {
#pragma unroll
        for (int nf = 0; nf < 4; ++nf) {
            const int Wp = w0 + nf * 16 + l15;
            const int dx = Wp & 1, wp1 = Wp >> 1;
#pragma unroll
            for (int r = 0; r < 4; ++r) {
                const int co = mf * 16 + l4 * 4 + r;
                const int n  = co * 4 + dy * 2 + dx;
                y_us[(((size_t)b * NCH + n) << 14) + (hp1 << 7) + wp1] = f2bf(acc[mf * 4 + nf][r]);
            }
        }
    }
}

// ---------------------------------------------------------------------------
// conv2: plain unit-stride grouped 3x3 over (y_us[n] bf16, m_us[n&3] fp32).
// 1D grid of 98304 blocks, block (128,2); XCD-contiguous remap so each XCD
// gets a contiguous (plane,row) chunk: 3-row stencil overlap + m_us plane
// become L2 hits.
// ---------------------------------------------------------------------------
__global__ __launch_bounds__(256) void conv2_kernel(
    const unsigned short* __restrict__ y_us, const float* __restrict__ m_us,
    const float* __restrict__ wproj, float* __restrict__ out)
{
    const int flat = blockIdx.x;                       // 0..98303
    const int j    = (flat & 7) * (B_ * NCH * (HO / 2) / 8) + (flat >> 3);
    const int bn   = j >> 6;                           // b*192 + n
    const int W    = threadIdx.x;
    const int H    = ((j & 63) << 1) + threadIdx.y;
    const int b    = bn / NCH;
    const int n    = bn - b * NCH;

    const float* wp = wproj + n * 18;                  // uniform -> s_load
    const unsigned short* yc = y_us + ((size_t)bn << 14);
    const float* mc = m_us + (((size_t)b * 4 + (n & 3)) << 14);

    float acc = 0.f;
#pragma unroll
    for (int kh = 0; kh < 3; ++kh) {
        const int hh = H + kh - 1;
        const bool rok = (unsigned)hh < (unsigned)HO;
#pragma unroll
        for (int kw = 0; kw < 3; ++kw) {
            const int ww = W + kw - 1;
            const bool ok = rok && ((unsigned)ww < (unsigned)WO);
            float yv = 0.f, mv = 0.f;
            if (ok) {
                yv = bf2f(yc[hh * WO + ww]);
                mv = mc[hh * WO + ww];
            }
            acc = fmaf(wp[kh * 3 + kw],     yv, acc);
            acc = fmaf(wp[9 + kh * 3 + kw], mv, acc);
        }
    }
    out[((size_t)bn << 14) + H * WO + W] = acc;
}

// ---------------------------------------------------------------------------
extern "C" void kernel_launch(void* const* d_in, const int* in_sizes, int n_in,
                              void* d_out, int out_size, void* d_ws, size_t ws_size,
                              hipStream_t stream) {
    const float* x      = (const float*)d_in[0];   // (8,96,256,256)
    const float* mask   = (const float*)d_in[1];   // (8,1,256,256)
    const float* w_body = (const float*)d_in[2];   // (48,96,3,3)
    const float* w_proj = (const float*)d_in[3];   // (192,2,3,3)
    float* out = (float*)d_out;                    // (8,192,128,128)

    // workspace layout
    char* p = (char*)d_ws;
    unsigned short* wbf  = (unsigned short*)p;     p += (9*CO1*CIN*2 + 255) & ~255ull;              // 83 KB
    float*          m_us = (float*)p;              p += ((size_t)B_*4*HO*WO*4 + 255) & ~255ull;     // 2 MB
    unsigned short* xt   = (unsigned short*)p;     p += ((size_t)B_*HP*HP*CIN*2 + 255) & ~255ull;   // 102 MB
    unsigned short* y_us = (unsigned short*)p;     // 50.3 MB (bf16 now)

    {   int nel = N1 + N2 + N3;
        prep_all<<<(nel + 255) / 256, 256, 0, stream>>>(w_body, wbf, mask, m_us, xt); }
    {   int nel = B_ * H_ * W_;
        transpose_x<<<nel / 256, 256, 0, stream>>>(x, xt); }
    {   conv1_mfma<<<B_ * H_, 256, 0, stream>>>(xt, wbf, y_us); }
    {   dim3 block(WO, 2, 1);
        conv2_kernel<<<B_ * NCH * (HO / 2), block, 0, stream>>>(y_us, m_us, w_proj, out); }
}